// Round 5
// baseline (478.079 us; speedup 1.0000x reference)
//
#include <hip/hip_runtime.h>
#include <stdint.h>

typedef short short8 __attribute__((ext_vector_type(8)));
typedef float f32x4 __attribute__((ext_vector_type(4)));

#define B_   16
#define C_   512
#define HW_  1024
#define PADP 1156   // 34*34
#define KC_  4608   // 9*512

__device__ __forceinline__ unsigned short f2bf(float f) {
  union { float f; unsigned u; } v; v.f = f;
  unsigned r = v.u + 0x7FFFu + ((v.u >> 16) & 1u);
  return (unsigned short)(r >> 16);
}
__device__ __forceinline__ float bf2f(unsigned short h) {
  union { unsigned u; float f; } v; v.u = ((unsigned)h) << 16;
  return v.f;
}

#define GLL16(g, l)                                                            \
  __builtin_amdgcn_global_load_lds(                                            \
      (const __attribute__((address_space(1))) void*)(g),                      \
      (__attribute__((address_space(3))) void*)(l), 16, 0, 0)

#define MFMA16(a, b, c) __builtin_amdgcn_mfma_f32_16x16x32_bf16((a), (b), (c), 0, 0, 0)

// ---------------- pack x: NCHW f32 -> padded NHWC bf16 (border pre-zeroed) --
__global__ void pack_x_kernel(const float* __restrict__ x,
                              unsigned short* __restrict__ xp) {
  __shared__ unsigned short lds[64][68];
  int b  = blockIdx.z;
  int c0 = blockIdx.y * 64;
  int p0 = blockIdx.x * 64;
  int tid = threadIdx.x;
  int pi = tid & 63, cq = tid >> 6;
#pragma unroll
  for (int i = 0; i < 16; ++i) {
    int cl = cq * 16 + i;
    lds[cl][pi] = f2bf(x[((size_t)(b * C_ + c0 + cl)) * HW_ + p0 + pi]);
  }
  __syncthreads();
  int ci = tid & 63, pq = tid >> 6;
#pragma unroll
  for (int j = 0; j < 16; ++j) {
    int pl = pq * 16 + j;
    int p  = p0 + pl;
    int pp = ((p >> 5) + 1) * 34 + (p & 31) + 1;
    xp[((size_t)(b * PADP + pp)) * C_ + c0 + ci] = lds[ci][pl];
  }
}

// ---------------- pack w_qkv: [oc][ic][t] f32 -> W2T[oc][t*512+ic] bf16 -----
__global__ void pack_wqkv_kernel(const float* __restrict__ w,
                                 unsigned short* __restrict__ w2t) {
  __shared__ unsigned short tmp[4608];
  int oc = blockIdx.x;
  for (int s = threadIdx.x; s < 4608; s += 256)
    tmp[s] = f2bf(w[(size_t)oc * 4608 + s]);
  __syncthreads();
  for (int d = threadIdx.x; d < 4608; d += 256) {
    int t = d >> 9, ic = d & 511;
    w2t[(size_t)oc * 4608 + d] = tmp[ic * 9 + t];
  }
}

// ---------------- pack w_proj: f32 -> bf16 ----------------------------------
__global__ void pack_wproj_kernel(const float* __restrict__ w,
                                  unsigned short* __restrict__ wp) {
  int i = blockIdx.x * 256 + threadIdx.x;
  wp[i] = f2bf(w[i]);
}

// ---------------- conv3x3 implicit GEMM (r1 structure: 128x128, 2-phase) ----
// C[m=pos][n=oc] = sum_k A[m][k] * B[n][k], k = tap*512+ic, BK=64
__launch_bounds__(256, 2)
__global__ void conv_qkv_kernel(const unsigned short* __restrict__ xp,
                                const unsigned short* __restrict__ w2t,
                                const float* __restrict__ bqkv,
                                unsigned short* __restrict__ qkb,
                                unsigned short* __restrict__ vT) {
  __shared__ unsigned short As[128 * 64];
  __shared__ unsigned short Bs[128 * 64];
  int b  = blockIdx.z;
  int m0 = blockIdx.y * 128;
  int n0 = blockIdx.x * 128;
  int tid = threadIdx.x;
  int w = tid >> 6, lane = tid & 63;
  int wm = w >> 1, wn = w & 1;
  int l15 = lane & 15, l4 = lane >> 4;
  f32x4 acc[4][4];
#pragma unroll
  for (int i = 0; i < 4; ++i)
#pragma unroll
    for (int j = 0; j < 4; ++j) acc[i][j] = (f32x4){0.f, 0.f, 0.f, 0.f};

  int sr = tid >> 3;  // staging row within 32-row group
  int sc = tid & 7;   // staging 16B chunk

  for (int kc = 0; kc < 72; ++kc) {
    int t   = kc >> 3;
    int ic0 = (kc & 7) << 6;
    int off = (t / 3 - 1) * 34 + (t % 3) - 1;
#pragma unroll
    for (int is = 0; is < 4; ++is) {
      int r  = is * 32 + sr;
      int p  = m0 + r;
      int pp = ((p >> 5) + 1) * 34 + (p & 31) + 1 + off;
      int cg = sc ^ (r & 7);
      GLL16(xp + ((size_t)(b * PADP + pp)) * C_ + ic0 + cg * 8,
            &As[is * 2048 + tid * 8]);
    }
#pragma unroll
    for (int is = 0; is < 4; ++is) {
      int r  = is * 32 + sr;
      int cg = sc ^ (r & 7);
      GLL16(w2t + (size_t)(n0 + r) * KC_ + kc * 64 + cg * 8,
            &Bs[is * 2048 + tid * 8]);
    }
    __syncthreads();
#pragma unroll
    for (int kk = 0; kk < 2; ++kk) {
      short8 af[4], bfr[4];
#pragma unroll
      for (int mi = 0; mi < 4; ++mi) {
        int r  = wm * 64 + mi * 16 + l15;
        int ck = kk * 4 + l4;
        af[mi] = *(const short8*)&As[r * 64 + ((ck ^ (r & 7)) << 3)];
      }
#pragma unroll
      for (int nj = 0; nj < 4; ++nj) {
        int r  = wn * 64 + nj * 16 + l15;
        int ck = kk * 4 + l4;
        bfr[nj] = *(const short8*)&Bs[r * 64 + ((ck ^ (r & 7)) << 3)];
      }
#pragma unroll
      for (int mi = 0; mi < 4; ++mi)
#pragma unroll
        for (int nj = 0; nj < 4; ++nj)
          acc[mi][nj] = MFMA16(af[mi], bfr[nj], acc[mi][nj]);
    }
    __syncthreads();
  }
  // epilogue: oc<1024 -> qkb[b][p][oc] ; oc>=1024 -> vT[b][oc-1024][p]
#pragma unroll
  for (int nj = 0; nj < 4; ++nj) {
    int col = n0 + wn * 64 + nj * 16 + l15;
    float bias = bqkv[col];
#pragma unroll
    for (int mi = 0; mi < 4; ++mi) {
      int prow = m0 + wm * 64 + mi * 16 + l4 * 4;
      if (col < 1024) {
#pragma unroll
        for (int rg = 0; rg < 4; ++rg)
          qkb[((size_t)(b * HW_ + prow + rg)) * 1024 + col] =
              f2bf(acc[mi][nj][rg] + bias);
      } else {
        ushort4 pk;
        pk.x = f2bf(acc[mi][nj][0] + bias);
        pk.y = f2bf(acc[mi][nj][1] + bias);
        pk.z = f2bf(acc[mi][nj][2] + bias);
        pk.w = f2bf(acc[mi][nj][3] + bias);
        *(ushort4*)&vT[((size_t)(b * C_ + col - 1024)) * HW_ + prow] = pk;
      }
    }
  }
}

// ---------------- attention + fused proj/residual ---------------------------
// Per block: batch b, 32 q-rows. Phases:
//  1: S = (Q K^T)*scale (S XOR-swizzled in LDS)
//  2: row softmax in place
//  3: O = P @ V  (acc in regs)
//  4: O -> LDS (reusing S, 32x512 bf16 swizzled); out = x + bproj + O @ Wp^T
// launch_bounds(512,4): cap VGPR at 128 so 2 blocks/CU co-reside (LDS 64 KiB
// x2 fits 160 KiB). At (512,2) the allocator drifted past 128 -> 1 block/CU
// -> two sequential grid rounds (~2x kernel time).
__launch_bounds__(512, 4)
__global__ void attn_kernel(const unsigned short* __restrict__ qkb,
                            const unsigned short* __restrict__ vT,
                            const unsigned short* __restrict__ wpb,
                            const float* __restrict__ bproj,
                            const float* __restrict__ x,
                            float* __restrict__ out) {
  __shared__ __attribute__((aligned(16))) unsigned short S[32 * 1024];
  int b  = blockIdx.y;
  int q0 = blockIdx.x * 32;
  int tid = threadIdx.x;
  int w = tid >> 6, lane = tid & 63;
  int l15 = lane & 15, l4 = lane >> 4;
  const unsigned short* qk = qkb + (size_t)b * HW_ * 1024;

  // ---- phase 1: S = (Q @ K^T) * scale, wave w owns kv-cols [w*128, +128)
  {
    f32x4 acc[2][8];
#pragma unroll
    for (int i = 0; i < 2; ++i)
#pragma unroll
      for (int j = 0; j < 8; ++j) acc[i][j] = (f32x4){0.f, 0.f, 0.f, 0.f};
    for (int kk = 0; kk < 16; ++kk) {
      int cbase = kk * 32 + l4 * 8;
      short8 af[2], bfr[8];
#pragma unroll
      for (int mi = 0; mi < 2; ++mi)
        af[mi] = *(const short8*)&qk[(size_t)(q0 + mi * 16 + l15) * 1024 + cbase];
#pragma unroll
      for (int nj = 0; nj < 8; ++nj)
        bfr[nj] = *(const short8*)&qk[(size_t)(w * 128 + nj * 16 + l15) * 1024 +
                                      512 + cbase];
#pragma unroll
      for (int mi = 0; mi < 2; ++mi)
#pragma unroll
        for (int nj = 0; nj < 8; ++nj)
          acc[mi][nj] = MFMA16(af[mi], bfr[nj], acc[mi][nj]);
    }
    const float scale = 0.044194173824159216f;  // 512^-0.5
#pragma unroll
    for (int mi = 0; mi < 2; ++mi)
#pragma unroll
      for (int nj = 0; nj < 8; ++nj)
#pragma unroll
        for (int rg = 0; rg < 4; ++rg) {
          int m = mi * 16 + l4 * 4 + rg;
          int n = w * 128 + nj * 16 + l15;
          S[m * 1024 + (n ^ ((m & 7) << 3))] = f2bf(acc[mi][nj][rg] * scale);
        }
  }
  __syncthreads();
  // ---- phase 2: row softmax (32 rows, 16 threads/row), P written in place
  {
    int row = tid >> 4, li = tid & 15;
    int xs = (row & 7) << 3;
    float v[64];
    float mx = -1e30f;
#pragma unroll
    for (int j = 0; j < 64; ++j) {
      v[j] = bf2f(S[row * 1024 + ((li + j * 16) ^ xs)]);
      mx = fmaxf(mx, v[j]);
    }
#pragma unroll
    for (int m = 1; m < 16; m <<= 1) mx = fmaxf(mx, __shfl_xor(mx, m, 64));
    float sum = 0.f;
#pragma unroll
    for (int j = 0; j < 64; ++j) { v[j] = __expf(v[j] - mx); sum += v[j]; }
#pragma unroll
    for (int m = 1; m < 16; m <<= 1) sum += __shfl_xor(sum, m, 64);
    float inv = 1.0f / sum;
#pragma unroll
    for (int j = 0; j < 64; ++j)
      S[row * 1024 + ((li + j * 16) ^ xs)] = f2bf(v[j] * inv);
  }
  __syncthreads();
  // ---- phase 3: O = P @ V, wave w owns channels [w*64, +64)
  f32x4 acc3[2][4];
  {
#pragma unroll
    for (int i = 0; i < 2; ++i)
#pragma unroll
      for (int j = 0; j < 4; ++j) acc3[i][j] = (f32x4){0.f, 0.f, 0.f, 0.f};
    const unsigned short* vtb = vT + (size_t)b * C_ * HW_;
    for (int kk = 0; kk < 32; ++kk) {
      int kb = kk * 32 + l4 * 8;
      short8 af[2], bfr[4];
#pragma unroll
      for (int mi = 0; mi < 2; ++mi) {
        int r = mi * 16 + l15;
        af[mi] = *(const short8*)&S[r * 1024 + (kb ^ ((r & 7) << 3))];
      }
#pragma unroll
      for (int nj = 0; nj < 4; ++nj)
        bfr[nj] = *(const short8*)&vtb[(size_t)(w * 64 + nj * 16 + l15) * 1024 + kb];
#pragma unroll
      for (int mi = 0; mi < 2; ++mi)
#pragma unroll
        for (int nj = 0; nj < 4; ++nj)
          acc3[mi][nj] = MFMA16(af[mi], bfr[nj], acc3[mi][nj]);
    }
  }
  __syncthreads();  // all waves finished reading S
  // ---- phase 4a: O -> LDS (first 32 KB of S), [32][512] bf16, XOR-swizzled
#pragma unroll
  for (int mi = 0; mi < 2; ++mi)
#pragma unroll
    for (int nj = 0; nj < 4; ++nj)
#pragma unroll
      for (int rg = 0; rg < 4; ++rg) {
        int p = mi * 16 + l4 * 4 + rg;
        int c = w * 64 + nj * 16 + l15;
        S[p * 512 + (c ^ ((p & 7) << 3))] = f2bf(acc3[mi][nj][rg]);
      }
  __syncthreads();
  // ---- phase 4b: out[b][oc][q0+p] = x + bproj[oc] + sum_ic Wp[oc][ic]*O[p][ic]
  // wave w owns oc in [w*64, +64): C[m=oc][n=p], K=512 (16 ksteps)
  {
    f32x4 acc2[4][2];
#pragma unroll
    for (int i = 0; i < 4; ++i)
#pragma unroll
      for (int j = 0; j < 2; ++j) acc2[i][j] = (f32x4){0.f, 0.f, 0.f, 0.f};
    for (int ks = 0; ks < 16; ++ks) {
      int kb = ks * 32 + l4 * 8;
      short8 af[4], bfr[2];
#pragma unroll
      for (int mi = 0; mi < 4; ++mi)
        af[mi] = *(const short8*)&wpb[(size_t)(w * 64 + mi * 16 + l15) * 512 + kb];
#pragma unroll
      for (int nj = 0; nj < 2; ++nj) {
        int r = nj * 16 + l15;
        bfr[nj] = *(const short8*)&S[r * 512 + (kb ^ ((r & 7) << 3))];
      }
#pragma unroll
      for (int mi = 0; mi < 4; ++mi)
#pragma unroll
        for (int nj = 0; nj < 2; ++nj)
          acc2[mi][nj] = MFMA16(af[mi], bfr[nj], acc2[mi][nj]);
    }
#pragma unroll
    for (int mi = 0; mi < 4; ++mi)
#pragma unroll
      for (int rg = 0; rg < 4; ++rg) {
        int oc = w * 64 + mi * 16 + l4 * 4 + rg;
        float bias = bproj[oc];
#pragma unroll
        for (int nj = 0; nj < 2; ++nj) {
          int p = q0 + nj * 16 + l15;
          size_t idx = ((size_t)(b * C_ + oc)) * HW_ + p;
          out[idx] = acc2[mi][nj][rg] + bias + x[idx];
        }
      }
  }
}

extern "C" void kernel_launch(void* const* d_in, const int* in_sizes, int n_in,
                              void* d_out, int out_size, void* d_ws,
                              size_t ws_size, hipStream_t stream) {
  const float* x      = (const float*)d_in[0];
  const float* w_qkv  = (const float*)d_in[1];
  const float* b_qkv  = (const float*)d_in[2];
  const float* w_proj = (const float*)d_in[3];
  const float* b_proj = (const float*)d_in[4];

  char* ws = (char*)d_ws;
  unsigned short* xp  = (unsigned short*)(ws + 0);          // 18,939,904
  unsigned short* w2t = (unsigned short*)(ws + 18939904);   // 14,155,776
  unsigned short* wpb = (unsigned short*)(ws + 33095680);   //    524,288
  unsigned short* qkb = (unsigned short*)(ws + 33619968);   // 33,554,432
  unsigned short* vT  = (unsigned short*)(ws + 67174400);   // 16,777,216
  float* out = (float*)d_out;

  hipMemsetAsync(xp, 0, (size_t)B_ * PADP * C_ * 2, stream);
  pack_x_kernel<<<dim3(16, 8, 16), 256, 0, stream>>>(x, xp);
  pack_wqkv_kernel<<<1536, 256, 0, stream>>>(w_qkv, w2t);
  pack_wproj_kernel<<<1024, 256, 0, stream>>>(w_proj, wpb);
  conv_qkv_kernel<<<dim3(12, 8, 16), 256, 0, stream>>>(xp, w2t, b_qkv, qkb, vT);
  attn_kernel<<<dim3(32, 16), 512, 0, stream>>>(qkb, vT, wpb, b_proj, x, out);
}

// Round 6
// 386.536 us; speedup vs baseline: 1.2368x; 1.2368x over previous
//
#include <hip/hip_runtime.h>
#include <stdint.h>

typedef short short8 __attribute__((ext_vector_type(8)));
typedef float f32x4 __attribute__((ext_vector_type(4)));

#define B_   16
#define C_   512
#define HW_  1024
#define PADP 1156   // 34*34
#define KC_  4608   // 9*512

__device__ __forceinline__ unsigned short f2bf(float f) {
  union { float f; unsigned u; } v; v.f = f;
  unsigned r = v.u + 0x7FFFu + ((v.u >> 16) & 1u);
  return (unsigned short)(r >> 16);
}
__device__ __forceinline__ float bf2f(unsigned short h) {
  union { unsigned u; float f; } v; v.u = ((unsigned)h) << 16;
  return v.f;
}

#define GLL16(g, l)                                                            \
  __builtin_amdgcn_global_load_lds(                                            \
      (const __attribute__((address_space(1))) void*)(g),                      \
      (__attribute__((address_space(3))) void*)(l), 16, 0, 0)

#define MFMA16(a, b, c) __builtin_amdgcn_mfma_f32_16x16x32_bf16((a), (b), (c), 0, 0, 0)

// ---------------- pack x: NCHW f32 -> padded NHWC bf16 (border pre-zeroed) --
__global__ void pack_x_kernel(const float* __restrict__ x,
                              unsigned short* __restrict__ xp) {
  __shared__ unsigned short lds[64][68];
  int b  = blockIdx.z;
  int c0 = blockIdx.y * 64;
  int p0 = blockIdx.x * 64;
  int tid = threadIdx.x;
  int pi = tid & 63, cq = tid >> 6;
#pragma unroll
  for (int i = 0; i < 16; ++i) {
    int cl = cq * 16 + i;
    lds[cl][pi] = f2bf(x[((size_t)(b * C_ + c0 + cl)) * HW_ + p0 + pi]);
  }
  __syncthreads();
  int ci = tid & 63, pq = tid >> 6;
#pragma unroll
  for (int j = 0; j < 16; ++j) {
    int pl = pq * 16 + j;
    int p  = p0 + pl;
    int pp = ((p >> 5) + 1) * 34 + (p & 31) + 1;
    xp[((size_t)(b * PADP + pp)) * C_ + c0 + ci] = lds[ci][pl];
  }
}

// ---------------- pack w_qkv: [oc][ic][t] f32 -> W2T[oc][t*512+ic] bf16 -----
__global__ void pack_wqkv_kernel(const float* __restrict__ w,
                                 unsigned short* __restrict__ w2t) {
  __shared__ unsigned short tmp[4608];
  int oc = blockIdx.x;
  for (int s = threadIdx.x; s < 4608; s += 256)
    tmp[s] = f2bf(w[(size_t)oc * 4608 + s]);
  __syncthreads();
  for (int d = threadIdx.x; d < 4608; d += 256) {
    int t = d >> 9, ic = d & 511;
    w2t[(size_t)oc * 4608 + d] = tmp[ic * 9 + t];
  }
}

// ---------------- pack w_proj: f32 -> bf16 ----------------------------------
__global__ void pack_wproj_kernel(const float* __restrict__ w,
                                  unsigned short* __restrict__ wp) {
  int i = blockIdx.x * 256 + threadIdx.x;
  wp[i] = f2bf(w[i]);
}

// ---------------- conv3x3 implicit GEMM (r1 structure: 128x128, 2-phase) ----
__launch_bounds__(256, 2)
__global__ void conv_qkv_kernel(const unsigned short* __restrict__ xp,
                                const unsigned short* __restrict__ w2t,
                                const float* __restrict__ bqkv,
                                unsigned short* __restrict__ qkb,
                                unsigned short* __restrict__ vT) {
  __shared__ unsigned short As[128 * 64];
  __shared__ unsigned short Bs[128 * 64];
  int b  = blockIdx.z;
  int m0 = blockIdx.y * 128;
  int n0 = blockIdx.x * 128;
  int tid = threadIdx.x;
  int w = tid >> 6, lane = tid & 63;
  int wm = w >> 1, wn = w & 1;
  int l15 = lane & 15, l4 = lane >> 4;
  f32x4 acc[4][4];
#pragma unroll
  for (int i = 0; i < 4; ++i)
#pragma unroll
    for (int j = 0; j < 4; ++j) acc[i][j] = (f32x4){0.f, 0.f, 0.f, 0.f};

  int sr = tid >> 3;
  int sc = tid & 7;

  for (int kc = 0; kc < 72; ++kc) {
    int t   = kc >> 3;
    int ic0 = (kc & 7) << 6;
    int off = (t / 3 - 1) * 34 + (t % 3) - 1;
#pragma unroll
    for (int is = 0; is < 4; ++is) {
      int r  = is * 32 + sr;
      int p  = m0 + r;
      int pp = ((p >> 5) + 1) * 34 + (p & 31) + 1 + off;
      int cg = sc ^ (r & 7);
      GLL16(xp + ((size_t)(b * PADP + pp)) * C_ + ic0 + cg * 8,
            &As[is * 2048 + tid * 8]);
    }
#pragma unroll
    for (int is = 0; is < 4; ++is) {
      int r  = is * 32 + sr;
      int cg = sc ^ (r & 7);
      GLL16(w2t + (size_t)(n0 + r) * KC_ + kc * 64 + cg * 8,
            &Bs[is * 2048 + tid * 8]);
    }
    __syncthreads();
#pragma unroll
    for (int kk = 0; kk < 2; ++kk) {
      short8 af[4], bfr[4];
#pragma unroll
      for (int mi = 0; mi < 4; ++mi) {
        int r  = wm * 64 + mi * 16 + l15;
        int ck = kk * 4 + l4;
        af[mi] = *(const short8*)&As[r * 64 + ((ck ^ (r & 7)) << 3)];
      }
#pragma unroll
      for (int nj = 0; nj < 4; ++nj) {
        int r  = wn * 64 + nj * 16 + l15;
        int ck = kk * 4 + l4;
        bfr[nj] = *(const short8*)&Bs[r * 64 + ((ck ^ (r & 7)) << 3)];
      }
#pragma unroll
      for (int mi = 0; mi < 4; ++mi)
#pragma unroll
        for (int nj = 0; nj < 4; ++nj)
          acc[mi][nj] = MFMA16(af[mi], bfr[nj], acc[mi][nj]);
    }
    __syncthreads();
  }
#pragma unroll
  for (int nj = 0; nj < 4; ++nj) {
    int col = n0 + wn * 64 + nj * 16 + l15;
    float bias = bqkv[col];
#pragma unroll
    for (int mi = 0; mi < 4; ++mi) {
      int prow = m0 + wm * 64 + mi * 16 + l4 * 4;
      if (col < 1024) {
#pragma unroll
        for (int rg = 0; rg < 4; ++rg)
          qkb[((size_t)(b * HW_ + prow + rg)) * 1024 + col] =
              f2bf(acc[mi][nj][rg] + bias);
      } else {
        ushort4 pk;
        pk.x = f2bf(acc[mi][nj][0] + bias);
        pk.y = f2bf(acc[mi][nj][1] + bias);
        pk.z = f2bf(acc[mi][nj][2] + bias);
        pk.w = f2bf(acc[mi][nj][3] + bias);
        *(ushort4*)&vT[((size_t)(b * C_ + col - 1024)) * HW_ + prow] = pk;
      }
    }
  }
}

// ---------------- attention: per block = one batch x 64 q-rows --------------
// QBLK=64 halves K/V L3 re-reads vs QBLK=32 (attn is L3-BW-bound).
// S tile [64][1024] bf16 = 128 KB LDS, XOR-swizzled; 1 block/CU, 8 waves.
__launch_bounds__(512, 2)
__global__ void attn_kernel(const unsigned short* __restrict__ qkb,
                            const unsigned short* __restrict__ vT,
                            unsigned short* __restrict__ hb) {
  __shared__ __attribute__((aligned(16))) unsigned short S[64 * 1024];
  int b  = blockIdx.y;
  int q0 = blockIdx.x * 64;
  int tid = threadIdx.x;
  int w = tid >> 6, lane = tid & 63;
  int l15 = lane & 15, l4 = lane >> 4;
  const unsigned short* qk = qkb + (size_t)b * HW_ * 1024;

  // ---- phase 1: S = (Q @ K^T) * scale, wave w owns kv-cols [w*128, +128)
  {
    f32x4 acc[4][8];
#pragma unroll
    for (int i = 0; i < 4; ++i)
#pragma unroll
      for (int j = 0; j < 8; ++j) acc[i][j] = (f32x4){0.f, 0.f, 0.f, 0.f};
    for (int kk = 0; kk < 16; ++kk) {
      int cbase = kk * 32 + l4 * 8;
      short8 af[4], bfr[8];
#pragma unroll
      for (int mi = 0; mi < 4; ++mi)
        af[mi] = *(const short8*)&qk[(size_t)(q0 + mi * 16 + l15) * 1024 + cbase];
#pragma unroll
      for (int nj = 0; nj < 8; ++nj)
        bfr[nj] = *(const short8*)&qk[(size_t)(w * 128 + nj * 16 + l15) * 1024 +
                                      512 + cbase];
#pragma unroll
      for (int mi = 0; mi < 4; ++mi)
#pragma unroll
        for (int nj = 0; nj < 8; ++nj)
          acc[mi][nj] = MFMA16(af[mi], bfr[nj], acc[mi][nj]);
    }
    const float scale = 0.044194173824159216f;  // 512^-0.5
#pragma unroll
    for (int mi = 0; mi < 4; ++mi)
#pragma unroll
      for (int nj = 0; nj < 8; ++nj)
#pragma unroll
        for (int rg = 0; rg < 4; ++rg) {
          int m = mi * 16 + l4 * 4 + rg;
          int n = w * 128 + nj * 16 + l15;
          S[m * 1024 + (n ^ ((m & 7) << 3))] = f2bf(acc[mi][nj][rg] * scale);
        }
  }
  __syncthreads();
  // ---- phase 2: row softmax, 64 rows in two passes of 32 (16 threads/row)
  {
#pragma unroll
    for (int rr = 0; rr < 2; ++rr) {
      int row = rr * 32 + (tid >> 4), li = tid & 15;
      int xs = (row & 7) << 3;
      float v[64];
      float mx = -1e30f;
#pragma unroll
      for (int j = 0; j < 64; ++j) {
        v[j] = bf2f(S[row * 1024 + ((li + j * 16) ^ xs)]);
        mx = fmaxf(mx, v[j]);
      }
#pragma unroll
      for (int m = 1; m < 16; m <<= 1) mx = fmaxf(mx, __shfl_xor(mx, m, 64));
      float sum = 0.f;
#pragma unroll
      for (int j = 0; j < 64; ++j) { v[j] = __expf(v[j] - mx); sum += v[j]; }
#pragma unroll
      for (int m = 1; m < 16; m <<= 1) sum += __shfl_xor(sum, m, 64);
      float inv = 1.0f / sum;
#pragma unroll
      for (int j = 0; j < 64; ++j)
        S[row * 1024 + ((li + j * 16) ^ xs)] = f2bf(v[j] * inv);
    }
  }
  __syncthreads();
  // ---- phase 3: O = P @ V, wave w owns channels [w*64, +64)
  {
    f32x4 acc3[4][4];
#pragma unroll
    for (int i = 0; i < 4; ++i)
#pragma unroll
      for (int j = 0; j < 4; ++j) acc3[i][j] = (f32x4){0.f, 0.f, 0.f, 0.f};
    const unsigned short* vtb = vT + (size_t)b * C_ * HW_;
    for (int kk = 0; kk < 32; ++kk) {
      int kb = kk * 32 + l4 * 8;
      short8 af[4], bfr[4];
#pragma unroll
      for (int mi = 0; mi < 4; ++mi) {
        int r = mi * 16 + l15;
        af[mi] = *(const short8*)&S[r * 1024 + (kb ^ ((r & 7) << 3))];
      }
#pragma unroll
      for (int nj = 0; nj < 4; ++nj)
        bfr[nj] = *(const short8*)&vtb[(size_t)(w * 64 + nj * 16 + l15) * 1024 + kb];
#pragma unroll
      for (int mi = 0; mi < 4; ++mi)
#pragma unroll
        for (int nj = 0; nj < 4; ++nj)
          acc3[mi][nj] = MFMA16(af[mi], bfr[nj], acc3[mi][nj]);
    }
#pragma unroll
    for (int mi = 0; mi < 4; ++mi)
#pragma unroll
      for (int nj = 0; nj < 4; ++nj)
#pragma unroll
        for (int rg = 0; rg < 4; ++rg) {
          int p = q0 + mi * 16 + l4 * 4 + rg;
          int c = w * 64 + nj * 16 + l15;
          hb[((size_t)(b * HW_ + p)) * C_ + c] = f2bf(acc3[mi][nj][rg]);
        }
  }
}

// ---------------- proj 1x1 + bias + residual, C[m=oc][n=pos] ----------------
__launch_bounds__(256, 2)
__global__ void proj_res_kernel(const unsigned short* __restrict__ hb,
                                const unsigned short* __restrict__ wp,
                                const float* __restrict__ bproj,
                                const float* __restrict__ x,
                                float* __restrict__ out) {
  __shared__ unsigned short As[128 * 64];
  __shared__ unsigned short Bs[128 * 64];
  int b   = blockIdx.z;
  int oc0 = blockIdx.y * 128;
  int p0  = blockIdx.x * 128;
  int tid = threadIdx.x;
  int w = tid >> 6, lane = tid & 63;
  int wm = w >> 1, wn = w & 1;
  int l15 = lane & 15, l4 = lane >> 4;
  f32x4 acc[4][4];
#pragma unroll
  for (int i = 0; i < 4; ++i)
#pragma unroll
    for (int j = 0; j < 4; ++j) acc[i][j] = (f32x4){0.f, 0.f, 0.f, 0.f};
  int sr = tid >> 3, sc = tid & 7;
  for (int kc = 0; kc < 8; ++kc) {
#pragma unroll
    for (int is = 0; is < 4; ++is) {
      int r  = is * 32 + sr;
      int cg = sc ^ (r & 7);
      GLL16(wp + (size_t)(oc0 + r) * 512 + kc * 64 + cg * 8,
            &As[is * 2048 + tid * 8]);
      GLL16(hb + ((size_t)(b * HW_ + p0 + r)) * 512 + kc * 64 + cg * 8,
            &Bs[is * 2048 + tid * 8]);
    }
    __syncthreads();
#pragma unroll
    for (int kk = 0; kk < 2; ++kk) {
      short8 af[4], bfr[4];
#pragma unroll
      for (int mi = 0; mi < 4; ++mi) {
        int r  = wm * 64 + mi * 16 + l15;
        int ck = kk * 4 + l4;
        af[mi] = *(const short8*)&As[r * 64 + ((ck ^ (r & 7)) << 3)];
      }
#pragma unroll
      for (int nj = 0; nj < 4; ++nj) {
        int r  = wn * 64 + nj * 16 + l15;
        int ck = kk * 4 + l4;
        bfr[nj] = *(const short8*)&Bs[r * 64 + ((ck ^ (r & 7)) << 3)];
      }
#pragma unroll
      for (int mi = 0; mi < 4; ++mi)
#pragma unroll
        for (int nj = 0; nj < 4; ++nj)
          acc[mi][nj] = MFMA16(af[mi], bfr[nj], acc[mi][nj]);
    }
    __syncthreads();
  }
#pragma unroll
  for (int mi = 0; mi < 4; ++mi)
#pragma unroll
    for (int rg = 0; rg < 4; ++rg) {
      int oc = oc0 + wm * 64 + mi * 16 + l4 * 4 + rg;
      float bias = bproj[oc];
#pragma unroll
      for (int nj = 0; nj < 4; ++nj) {
        int p = p0 + wn * 64 + nj * 16 + l15;
        size_t idx = ((size_t)(b * C_ + oc)) * HW_ + p;
        out[idx] = acc[mi][nj][rg] + bias + x[idx];
      }
    }
}

extern "C" void kernel_launch(void* const* d_in, const int* in_sizes, int n_in,
                              void* d_out, int out_size, void* d_ws,
                              size_t ws_size, hipStream_t stream) {
  const float* x      = (const float*)d_in[0];
  const float* w_qkv  = (const float*)d_in[1];
  const float* b_qkv  = (const float*)d_in[2];
  const float* w_proj = (const float*)d_in[3];
  const float* b_proj = (const float*)d_in[4];

  char* ws = (char*)d_ws;
  unsigned short* xp  = (unsigned short*)(ws + 0);          // 18,939,904
  unsigned short* w2t = (unsigned short*)(ws + 18939904);   // 14,155,776
  unsigned short* wpb = (unsigned short*)(ws + 33095680);   //    524,288
  unsigned short* qkb = (unsigned short*)(ws + 33619968);   // 33,554,432
  unsigned short* vT  = (unsigned short*)(ws + 67174400);   // 16,777,216
  unsigned short* hb  = (unsigned short*)(ws + 83951616);   // 16,777,216
  float* out = (float*)d_out;

  hipMemsetAsync(xp, 0, (size_t)B_ * PADP * C_ * 2, stream);
  pack_x_kernel<<<dim3(16, 8, 16), 256, 0, stream>>>(x, xp);
  pack_wqkv_kernel<<<1536, 256, 0, stream>>>(w_qkv, w2t);
  pack_wproj_kernel<<<1024, 256, 0, stream>>>(w_proj, wpb);
  conv_qkv_kernel<<<dim3(12, 8, 16), 256, 0, stream>>>(xp, w2t, b_qkv, qkb, vT);
  attn_kernel<<<dim3(16, 16), 512, 0, stream>>>(qkb, vT, hb);
  proj_res_kernel<<<dim3(8, 4, 16), 256, 0, stream>>>(hb, wpb, b_proj, x, out);
}